// Round 5
// baseline (644.443 us; speedup 1.0000x reference)
//
#include <hip/hip_runtime.h>
#include <hip/hip_bf16.h>

// SDE Euler-Maruyama: x_{k+1} = x_k + dt*(x_k @ A^T) + (sigma*sqrt(dt))*dW_k
// out[0] = x0, out[k+1] = x_{k+1}, out shape [1001, 1024, 256].
//
// R1 880us: 1 wave/SIMD latency-bound. R2 849us: lgkm-only barriers.
// R3 973us: C/D-layout update regressed (scalar I/O, no TLP).
// R4 632us: 512thr = 2 waves/SIMD; MfmaUtil 35%, occ 23.5%.
// R5: 1024thr = 16 waves = 4 waves/SIMD. Wave owns 16 MFMA cols (one 8-deep
// chain, bfr 32 VGPR); update thread owns (path, 1 dim) -> scalar coalesced
// global I/O (256B/wave). Structure otherwise identical to R4.

typedef __attribute__((ext_vector_type(4))) float fvec4;
typedef __attribute__((ext_vector_type(8))) short svec8;
typedef __attribute__((ext_vector_type(4))) float f32x4;

constexpr int D = 256;
constexpr int BATCH = 1024;
constexpr int BD = BATCH * D;
constexpr int NSTEPS = 1000;
constexpr float DT = 0.001f;
constexpr float SQRT_DT = 0.03162277660168379f;  // sqrt(0.001)

__device__ __forceinline__ unsigned short f2bf(float f) {
  // round-to-nearest-even f32 -> bf16
  unsigned int u = __float_as_uint(f);
  u += 0x7FFFu + ((u >> 16) & 1u);
  return (unsigned short)(u >> 16);
}

// LDS-only barrier: no vmcnt drain (global loads/stores stay in flight).
__device__ __forceinline__ void lds_barrier() {
  __builtin_amdgcn_sched_barrier(0);
  asm volatile("s_waitcnt lgkmcnt(0)" ::: "memory");
  __builtin_amdgcn_s_barrier();
  __builtin_amdgcn_sched_barrier(0);
}

__global__ __launch_bounds__(1024, 4)
void sde_em_kernel(const float* __restrict__ x0, const float* __restrict__ Amat,
                   const float* __restrict__ sigma, const float* __restrict__ dW,
                   float* __restrict__ out) {
  // xb: double-buffered bf16 x, 4 paths x 256 dims, XOR-swizzled (^ row<<5)
  __shared__ __align__(16) unsigned short xb[2][4 * 256];
  // dr: fp32 drift tile, 4 paths x 256 dims
  __shared__ __align__(16) float dr[4 * 256];

  const int t = threadIdx.x;
  const int w = t >> 6;          // wave 0..15
  const int l = t & 63;
  const int l16 = l & 15;

  // ---- MFMA role: wave w owns output cols w*16 .. w*16+15 ----
  // B-frag (16x16x32): lane holds col n = l&15, k = (l>>4)*8 + i
  svec8 bfr[8];
  {
    const int n = (w << 4) + l16;
    const int kb = (l >> 4) << 3;
#pragma unroll
    for (int kt = 0; kt < 8; ++kt) {
      const float* src = Amat + (size_t)n * D + (kt << 5) + kb;
      fvec4 a0 = *(const fvec4*)(src);
      fvec4 a1 = *(const fvec4*)(src + 4);
      svec8 b;
      b[0] = (short)f2bf(a0[0]); b[1] = (short)f2bf(a0[1]);
      b[2] = (short)f2bf(a0[2]); b[3] = (short)f2bf(a0[3]);
      b[4] = (short)f2bf(a1[0]); b[5] = (short)f2bf(a1[1]);
      b[6] = (short)f2bf(a1[2]); b[7] = (short)f2bf(a1[3]);
      bfr[kt] = b;
    }
  }

  // ---- update role: thread owns (path pt, dim cb) ----
  const int pt = t >> 8;         // path 0..3
  const int cb = t & 255;        // dim 0..255
  const size_t goff = (size_t)((blockIdx.x << 2) + pt) * D + cb;
  const int xwi = (pt << 8) + (cb ^ (pt << 5));  // xb write index (u16)

  const float sg = sigma[cb] * SQRT_DT;
  float xs = x0[goff];

  // out[0] = x0
  __builtin_nontemporal_store(xs, out + goff);

  // seed xb[0]
  xb[0][xwi] = f2bf(xs);

  // A-frag read addressing: row rr = (l&15)&3 (rows 4-15 duplicate paths 0-3;
  // their C/D rows land in lanes >= 16, never stored)
  const int rr = l16 & 3;
  const int q = l >> 4;

  // 2-deep dW prefetch
  float dwA = __builtin_nontemporal_load(dW + goff);
  float dwB = __builtin_nontemporal_load(dW + BD + goff);

  __syncthreads();

#define STEP(n_, CUR, RB, WB)                                                  \
  {                                                                            \
    const int nn_ = ((n_) + 2 < NSTEPS) ? ((n_) + 2) : (NSTEPS - 1);           \
    float nw_ = __builtin_nontemporal_load(dW + (size_t)nn_ * BD + goff);      \
    f32x4 acc = (f32x4){0.f, 0.f, 0.f, 0.f};                                   \
    _Pragma("unroll") for (int kt = 0; kt < 8; ++kt) {                         \
      svec8 a = *(const svec8*)                                                \
          &xb[RB][(rr << 8) + (((kt << 5) + (q << 3)) ^ (rr << 5))];           \
      acc = __builtin_amdgcn_mfma_f32_16x16x32_bf16(a, bfr[kt], acc, 0, 0, 0); \
    }                                                                          \
    /* C/D: col = lane&15 (output dim), row = path = reg (lanes 0-15) */       \
    if (l < 16) {                                                              \
      _Pragma("unroll") for (int r = 0; r < 4; ++r)                            \
          dr[(r << 8) + (w << 4) + l16] = acc[r];                              \
    }                                                                          \
    lds_barrier();                                                             \
    float df = dr[(pt << 8) + cb];                                             \
    xs = __builtin_fmaf(DT, df, __builtin_fmaf(sg, CUR, xs));                  \
    __builtin_nontemporal_store(xs, out + (size_t)((n_) + 1) * BD + goff);     \
    xb[WB][xwi] = f2bf(xs);                                                    \
    CUR = nw_;                                                                 \
    lds_barrier();                                                             \
  }

  for (int n = 0; n < NSTEPS; n += 2) {
    STEP(n, dwA, 0, 1);
    STEP(n + 1, dwB, 1, 0);
  }
#undef STEP
}

extern "C" void kernel_launch(void* const* d_in, const int* in_sizes, int n_in,
                              void* d_out, int out_size, void* d_ws, size_t ws_size,
                              hipStream_t stream) {
  const float* x0    = (const float*)d_in[0];
  const float* Amat  = (const float*)d_in[1];
  const float* sigma = (const float*)d_in[2];
  const float* dW    = (const float*)d_in[3];
  float* out = (float*)d_out;
  sde_em_kernel<<<dim3(256), dim3(1024), 0, stream>>>(x0, Amat, sigma, dW, out);
}